// Round 3
// baseline (945.334 us; speedup 1.0000x reference)
//
#include <hip/hip_runtime.h>
#include <math.h>

typedef unsigned short u16;
typedef unsigned int u32;
typedef __attribute__((ext_vector_type(8))) short short8;
typedef __attribute__((ext_vector_type(4))) float f32x4;

#define C_ 128
#define NTOK 200704   // B*H*W = 64*56*56
#define NMT  12544    // NTOK/16 M-tiles
#define NWIN 4096     // B * 64
#define SCALE_ 0.17677669529663687f

static __device__ __forceinline__ float bf2f(u16 u) {
    return __uint_as_float(((u32)u) << 16);
}
static __device__ __forceinline__ u16 f2bf(float f) {
    u32 u = __float_as_uint(f);
    u32 r = u + 0x7FFFu + ((u >> 16) & 1u);
    return (u16)(r >> 16);
}

// ---------------- plain weight transpose to bf16 [N][K] ----------------
__global__ void k_transpose(const float* __restrict__ W, u16* __restrict__ Wt, int K, int N) {
    int i = blockIdx.x * 256 + threadIdx.x;
    if (i >= K * N) return;
    int k = i / N, n = i % N;
    Wt[(size_t)n * K + k] = f2bf(W[i]);
}

// ---------------- LN-folding prep: Wt[n][k]=bf16(W[k][n]*g[k]); bout[n]=b[n]+sum_k be[k]*W[k][n]
__global__ __launch_bounds__(128) void k_prep(const float* __restrict__ W,
                                              const float* __restrict__ g,
                                              const float* __restrict__ be,
                                              const float* __restrict__ b,
                                              u16* __restrict__ Wt,
                                              float* __restrict__ bout, int N) {
    int n = blockIdx.x, k = threadIdx.x;  // K = 128 fixed
    float w = W[(size_t)k * N + n];
    Wt[(size_t)n * 128 + k] = f2bf(w * g[k]);
    __shared__ float red[128];
    red[k] = be[k] * w;
    __syncthreads();
    for (int s = 64; s > 0; s >>= 1) {
        if (k < s) red[k] += red[k + s];
        __syncthreads();
    }
    if (k == 0) bout[n] = b[n] + red[0];
}

// ---------------- B-fragment loader (wave's N-slice, registers) ----------------
template <int KD, int NN>
static __device__ __forceinline__ void load_bfrag(const u16* __restrict__ Wt, int col0, int lane,
                                                  short8 (&bf)[NN][KD / 32]) {
    constexpr int NK = KD / 32;
    const int colb = lane & 15, kb = (lane >> 4) * 8;
#pragma unroll
    for (int n = 0; n < NN; ++n)
#pragma unroll
        for (int ks = 0; ks < NK; ++ks)
            bf[n][ks] = *(const short8*)(Wt + (size_t)(col0 + n * 16 + colb) * KD + ks * 32 + kb);
}

// ---------------- QKV GEMM with fused LN1 + shift + window partition ----------------
// 8 waves/block, wave owns 48 cols. Reads x (f32) directly at window-ordered rows.
__global__ __launch_bounds__(512) void k_qkv(const float* __restrict__ x,
                                             const u16* __restrict__ qkvT,
                                             const float* __restrict__ bq,
                                             u16* __restrict__ qkv) {
    int lane = threadIdx.x & 63, wv = threadIdx.x >> 6;
    int colb = lane & 15, q = lane >> 4;
    int col0 = wv * 48;
    short8 bf[3][4];
    load_bfrag<128, 3>(qkvT, col0, lane, bf);
    float bias[3];
#pragma unroll
    for (int n = 0; n < 3; ++n) bias[n] = bq[col0 + n * 16 + colb];

    float cur[32], nxt[32];
    auto loadA = [&](int mt, float* dst) {
        int m = mt * 16 + colb;          // window-ordered row
        int w = m / 49, nn = m - w * 49;
        int b = w >> 6, wi = w & 63;
        int ys = (wi >> 3) * 7 + nn / 7, xs = (wi & 7) * 7 + nn % 7;
        int y = ys + 3; if (y >= 56) y -= 56;
        int xx = xs + 3; if (xx >= 56) xx -= 56;
        const float* px = x + ((size_t)b * 3136 + y * 56 + xx) * 128 + q * 8;
#pragma unroll
        for (int ks = 0; ks < 4; ++ks) {
            *(float4*)(dst + ks * 8)     = *(const float4*)(px + ks * 32);
            *(float4*)(dst + ks * 8 + 4) = *(const float4*)(px + ks * 32 + 4);
        }
    };
    loadA(blockIdx.x, cur);
#pragma unroll 1
    for (int mt = blockIdx.x; mt < NMT; mt += gridDim.x) {
        int mtn = mt + gridDim.x;
        if (mtn < NMT) loadA(mtn, nxt);
        float s = 0.f, s2 = 0.f;
#pragma unroll
        for (int i = 0; i < 32; ++i) { s += cur[i]; s2 += cur[i] * cur[i]; }
        s  += __shfl_xor(s, 16, 64);  s  += __shfl_xor(s, 32, 64);
        s2 += __shfl_xor(s2, 16, 64); s2 += __shfl_xor(s2, 32, 64);
        float mu = s * (1.f / 128.f);
        float rs = rsqrtf(s2 * (1.f / 128.f) - mu * mu + 1e-3f);
        short8 af[4];
#pragma unroll
        for (int ks = 0; ks < 4; ++ks)
#pragma unroll
            for (int e = 0; e < 8; ++e)
                af[ks][e] = (short)f2bf((cur[ks * 8 + e] - mu) * rs);
        f32x4 acc[3];
#pragma unroll
        for (int n = 0; n < 3; ++n) acc[n] = (f32x4){0.f, 0.f, 0.f, 0.f};
#pragma unroll
        for (int ks = 0; ks < 4; ++ks)
#pragma unroll
            for (int n = 0; n < 3; ++n)
                acc[n] = __builtin_amdgcn_mfma_f32_16x16x32_bf16(af[ks], bf[n][ks], acc[n], 0, 0, 0);
#pragma unroll
        for (int n = 0; n < 3; ++n) {
            int col = col0 + n * 16 + colb;
#pragma unroll
            for (int r = 0; r < 4; ++r)
                qkv[(size_t)(mt * 16 + q * 4 + r) * 384 + col] = f2bf(acc[n][r] + bias[n]);
        }
#pragma unroll
        for (int i = 0; i < 32; ++i) cur[i] = nxt[i];
    }
}

// ---------------- window attention: 1 block/window, 1 wave/head ----------------
__global__ __launch_bounds__(256) void k_attn(const u16* __restrict__ qkv,
                                              const float* __restrict__ relTab,
                                              u16* __restrict__ outA) {
    __shared__ u16 qs[49 * 128];
    __shared__ u16 vs[49 * 128];
    __shared__ float biasl[169 * 4];
    __shared__ float pl[4][2][64];
    int tid = threadIdx.x;
    int w = blockIdx.x;
    const u16* base = qkv + (size_t)w * 49 * 384;
    for (int idx = tid; idx < 49 * 16; idx += 256) {
        int r = idx >> 4, c8 = (idx & 15) * 8;
        *(short8*)(qs + r * 128 + c8) = *(const short8*)(base + r * 384 + c8);
        *(short8*)(vs + r * 128 + c8) = *(const short8*)(base + r * 384 + 256 + c8);
    }
    for (int idx = tid; idx < 169 * 4; idx += 256) biasl[idx] = relTab[idx];
    __syncthreads();

    int lane = tid & 63, h = tid >> 6;
    int wi = w & 63, wr = wi >> 3, wc = wi & 7;
    int j = lane < 49 ? lane : 48;
    bool jvalid = lane < 49;

    float kf[32];
    {
        const u16* kp = base + (size_t)j * 384 + 128 + h * 32;
#pragma unroll
        for (int t4 = 0; t4 < 4; ++t4) {
            short8 kk = *(const short8*)(kp + t4 * 8);
#pragma unroll
            for (int e = 0; e < 8; ++e) kf[t4 * 8 + e] = bf2f((u16)kk[e]);
        }
    }
    int d = lane & 31;
    float vf[49];
#pragma unroll
    for (int jj = 0; jj < 49; ++jj) vf[jj] = bf2f(vs[jj * 128 + h * 32 + d]);

    int yj = j / 7, xj = j % 7;
    int gy = wr * 7 + yj, gx = wc * 7 + xj;
    int cj = (gy < 49 ? 0 : (gy < 53 ? 1 : 2)) * 3 + (gx < 49 ? 0 : (gx < 53 ? 1 : 2));

#pragma unroll 1
    for (int r0 = 0; r0 < 49; r0 += 2) {
        int r1 = (r0 + 1 < 49) ? r0 + 1 : 48;
        float s0 = 0.f, s1 = 0.f;
#pragma unroll
        for (int t4 = 0; t4 < 4; ++t4) {
            short8 q0v = *(const short8*)(qs + r0 * 128 + h * 32 + t4 * 8);
            short8 q1v = *(const short8*)(qs + r1 * 128 + h * 32 + t4 * 8);
#pragma unroll
            for (int e = 0; e < 8; ++e) {
                float kv = kf[t4 * 8 + e];
                s0 += bf2f((u16)q0v[e]) * kv;
                s1 += bf2f((u16)q1v[e]) * kv;
            }
        }
        int yi0 = r0 / 7, xi0 = r0 % 7, yi1 = r1 / 7, xi1 = r1 % 7;
        int g0y = wr * 7 + yi0, g0x = wc * 7 + xi0;
        int g1y = wr * 7 + yi1, g1x = wc * 7 + xi1;
        int c0 = (g0y < 49 ? 0 : (g0y < 53 ? 1 : 2)) * 3 + (g0x < 49 ? 0 : (g0x < 53 ? 1 : 2));
        int c1 = (g1y < 49 ? 0 : (g1y < 53 ? 1 : 2)) * 3 + (g1x < 49 ? 0 : (g1x < 53 ? 1 : 2));
        s0 = s0 * SCALE_ + biasl[((yi0 - yj + 6) * 13 + (xi0 - xj + 6)) * 4 + h] + (c0 == cj ? 0.f : -100.f);
        s1 = s1 * SCALE_ + biasl[((yi1 - yj + 6) * 13 + (xi1 - xj + 6)) * 4 + h] + (c1 == cj ? 0.f : -100.f);
        if (!jvalid) { s0 = -1e30f; s1 = -1e30f; }
        float m0 = s0, m1 = s1;
#pragma unroll
        for (int off = 32; off; off >>= 1) {
            m0 = fmaxf(m0, __shfl_xor(m0, off, 64));
            m1 = fmaxf(m1, __shfl_xor(m1, off, 64));
        }
        float e0 = jvalid ? __expf(s0 - m0) : 0.f;
        float e1 = jvalid ? __expf(s1 - m1) : 0.f;
        float t0 = e0, t1 = e1;
#pragma unroll
        for (int off = 32; off; off >>= 1) {
            t0 += __shfl_xor(t0, off, 64);
            t1 += __shfl_xor(t1, off, 64);
        }
        pl[h][0][lane] = e0 / t0;
        pl[h][1][lane] = e1 / t1;
        int half = lane >> 5;
        const float* pp = &pl[h][half][0];
        float o = 0.f;
#pragma unroll
        for (int jj = 0; jj < 49; ++jj) o += pp[jj] * vf[jj];
        int rr = half ? r1 : r0;
        if (half == 0 || r0 + 1 < 49)
            outA[((size_t)w * 49 + rr) * C_ + h * 32 + d] = f2bf(o);
    }
}

// ---------------- proj GEMM + reverse/roll + residual -> x1 (f32) ----------------
// 8 waves/block, wave owns 16 cols.
__global__ __launch_bounds__(512) void k_proj(const u16* __restrict__ attnO,
                                              const u16* __restrict__ projT,
                                              const float* __restrict__ bproj,
                                              const float* __restrict__ x,
                                              float* __restrict__ x1) {
    int lane = threadIdx.x & 63, wv = threadIdx.x >> 6;
    int colb = lane & 15, q = lane >> 4;
    int col0 = wv * 16;
    short8 bf[1][4];
    load_bfrag<128, 1>(projT, col0, lane, bf);
    float bias = bproj[col0 + colb];
    short8 cur[4], nxt[4];
    auto loadA = [&](int mt, short8* dst) {
        const u16* pa = attnO + (size_t)(mt * 16 + colb) * 128 + q * 8;
#pragma unroll
        for (int ks = 0; ks < 4; ++ks) dst[ks] = *(const short8*)(pa + ks * 32);
    };
    loadA(blockIdx.x, cur);
#pragma unroll 1
    for (int mt = blockIdx.x; mt < NMT; mt += gridDim.x) {
        int mtn = mt + gridDim.x;
        if (mtn < NMT) loadA(mtn, nxt);
        f32x4 acc = {0.f, 0.f, 0.f, 0.f};
#pragma unroll
        for (int ks = 0; ks < 4; ++ks)
            acc = __builtin_amdgcn_mfma_f32_16x16x32_bf16(cur[ks], bf[0][ks], acc, 0, 0, 0);
        int col = col0 + colb;
#pragma unroll
        for (int r = 0; r < 4; ++r) {
            int m = mt * 16 + q * 4 + r;
            int w = m / 49, nn = m - w * 49;
            int b = w >> 6, wi = w & 63;
            int ys = (wi >> 3) * 7 + nn / 7, xs = (wi & 7) * 7 + nn % 7;
            int y = ys + 3; if (y >= 56) y -= 56;
            int xx = xs + 3; if (xx >= 56) xx -= 56;
            size_t tok = (size_t)b * 3136 + y * 56 + xx;
            x1[tok * 128 + col] = acc[r] + bias + x[tok * 128 + col];
        }
#pragma unroll
        for (int ks = 0; ks < 4; ++ks) cur[ks] = nxt[ks];
    }
}

// ---------------- FC1 with fused LN2 + exact GELU ----------------
// 2-way col split across blocks; 8 waves, wave owns 32 cols.
__global__ __launch_bounds__(512) void k_fc1(const float* __restrict__ x1,
                                             const u16* __restrict__ fc1T,
                                             const float* __restrict__ b1,
                                             u16* __restrict__ h1) {
    int lane = threadIdx.x & 63, wv = threadIdx.x >> 6;
    int colb = lane & 15, q = lane >> 4;
    int half = blockIdx.x & 1;
    int col0 = half * 256 + wv * 32;
    int mt0 = blockIdx.x >> 1, stride = gridDim.x >> 1;
    short8 bf[2][4];
    load_bfrag<128, 2>(fc1T, col0, lane, bf);
    float bias[2] = {b1[col0 + colb], b1[col0 + 16 + colb]};
    float cur[32], nxt[32];
    auto loadA = [&](int mt, float* dst) {
        const float* px = x1 + (size_t)(mt * 16 + colb) * 128 + q * 8;
#pragma unroll
        for (int ks = 0; ks < 4; ++ks) {
            *(float4*)(dst + ks * 8)     = *(const float4*)(px + ks * 32);
            *(float4*)(dst + ks * 8 + 4) = *(const float4*)(px + ks * 32 + 4);
        }
    };
    loadA(mt0, cur);
#pragma unroll 1
    for (int mt = mt0; mt < NMT; mt += stride) {
        int mtn = mt + stride;
        if (mtn < NMT) loadA(mtn, nxt);
        float s = 0.f, s2 = 0.f;
#pragma unroll
        for (int i = 0; i < 32; ++i) { s += cur[i]; s2 += cur[i] * cur[i]; }
        s  += __shfl_xor(s, 16, 64);  s  += __shfl_xor(s, 32, 64);
        s2 += __shfl_xor(s2, 16, 64); s2 += __shfl_xor(s2, 32, 64);
        float mu = s * (1.f / 128.f);
        float rs = rsqrtf(s2 * (1.f / 128.f) - mu * mu + 1e-3f);
        short8 af[4];
#pragma unroll
        for (int ks = 0; ks < 4; ++ks)
#pragma unroll
            for (int e = 0; e < 8; ++e)
                af[ks][e] = (short)f2bf((cur[ks * 8 + e] - mu) * rs);
        f32x4 acc[2];
#pragma unroll
        for (int n = 0; n < 2; ++n) acc[n] = (f32x4){0.f, 0.f, 0.f, 0.f};
#pragma unroll
        for (int ks = 0; ks < 4; ++ks)
#pragma unroll
            for (int n = 0; n < 2; ++n)
                acc[n] = __builtin_amdgcn_mfma_f32_16x16x32_bf16(af[ks], bf[n][ks], acc[n], 0, 0, 0);
#pragma unroll
        for (int n = 0; n < 2; ++n) {
            int col = col0 + n * 16 + colb;
#pragma unroll
            for (int r = 0; r < 4; ++r) {
                float t = acc[n][r] + bias[n];
                float g = 0.5f * t * (1.f + erff(t * 0.70710678118654752f));
                h1[(size_t)(mt * 16 + q * 4 + r) * 512 + col] = f2bf(g);
            }
        }
#pragma unroll
        for (int i = 0; i < 32; ++i) cur[i] = nxt[i];
    }
}

// ---------------- FC2 + final residual ----------------
// 8 waves, wave owns 16 cols; K=512 -> 16 A-loads all in flight per tile.
__global__ __launch_bounds__(512) void k_fc2(const u16* __restrict__ h1,
                                             const u16* __restrict__ fc2T,
                                             const float* __restrict__ b2,
                                             const float* __restrict__ x1,
                                             float* __restrict__ out) {
    int lane = threadIdx.x & 63, wv = threadIdx.x >> 6;
    int colb = lane & 15, q = lane >> 4;
    int col0 = wv * 16;
    short8 bf[1][16];
    load_bfrag<512, 1>(fc2T, col0, lane, bf);
    float bias = b2[col0 + colb];
#pragma unroll 1
    for (int mt = blockIdx.x; mt < NMT; mt += gridDim.x) {
        const u16* pa = h1 + (size_t)(mt * 16 + colb) * 512 + q * 8;
        short8 af[16];
#pragma unroll
        for (int ks = 0; ks < 16; ++ks) af[ks] = *(const short8*)(pa + ks * 32);
        f32x4 acc = {0.f, 0.f, 0.f, 0.f};
#pragma unroll
        for (int ks = 0; ks < 16; ++ks)
            acc = __builtin_amdgcn_mfma_f32_16x16x32_bf16(af[ks], bf[0][ks], acc, 0, 0, 0);
        int col = col0 + colb;
#pragma unroll
        for (int r = 0; r < 4; ++r) {
            size_t m = (size_t)mt * 16 + q * 4 + r;
            out[m * 128 + col] = x1[m * 128 + col] + acc[r] + bias;
        }
    }
}

extern "C" void kernel_launch(void* const* d_in, const int* in_sizes, int n_in,
                              void* d_out, int out_size, void* d_ws, size_t ws_size,
                              hipStream_t stream) {
    const float* x    = (const float*)d_in[0];
    const float* g1   = (const float*)d_in[1];
    const float* be1  = (const float*)d_in[2];
    const float* Wqkv = (const float*)d_in[3];
    const float* bqkv = (const float*)d_in[4];
    const float* relT = (const float*)d_in[5];
    const float* Wproj= (const float*)d_in[6];
    const float* bproj= (const float*)d_in[7];
    const float* g2   = (const float*)d_in[8];
    const float* be2  = (const float*)d_in[9];
    const float* Wfc1 = (const float*)d_in[10];
    const float* bfc1 = (const float*)d_in[11];
    const float* Wfc2 = (const float*)d_in[12];
    const float* bfc2 = (const float*)d_in[13];
    float* out = (float*)d_out;
    char* ws = (char*)d_ws;

    u16* qkvb  = (u16*)(ws + 0);              // 154,140,672  dead after k_attn
    u16* attnO = (u16*)(ws + 154140672ULL);   //  51,380,224  dead after k_proj
    float* x1  = (float*)(ws + 205520896ULL); // 102,760,448  lives to k_fc2
    u16* h1    = (u16*)(ws + 0);              // 205,520,896  overwrites qkvb/attnO
    char* wb   = ws + 308281344ULL;
    u16* qkvT  = (u16*)(wb);                  // 98,304
    float* bq  = (float*)(wb + 98304);        // 1,536
    u16* fc1T  = (u16*)(wb + 99840);          // 131,072
    float* bf1 = (float*)(wb + 230912);       // 2,048
    u16* projT = (u16*)(wb + 232960);         // 32,768
    u16* fc2T  = (u16*)(wb + 265728);         // 131,072

    k_prep<<<dim3(384), dim3(128), 0, stream>>>(Wqkv, g1, be1, bqkv, qkvT, bq, 384);
    k_prep<<<dim3(512), dim3(128), 0, stream>>>(Wfc1, g2, be2, bfc1, fc1T, bf1, 512);
    k_transpose<<<dim3((128 * 128 + 255) / 256), dim3(256), 0, stream>>>(Wproj, projT, 128, 128);
    k_transpose<<<dim3((512 * 128 + 255) / 256), dim3(256), 0, stream>>>(Wfc2, fc2T, 512, 128);

    k_qkv <<<dim3(1568), dim3(512), 0, stream>>>(x, qkvT, bq, qkvb);
    k_attn<<<dim3(NWIN), dim3(256), 0, stream>>>(qkvb, relT, attnO);
    k_proj<<<dim3(1568), dim3(512), 0, stream>>>(attnO, projT, bproj, x, x1);
    k_fc1 <<<dim3(3136), dim3(512), 0, stream>>>(x1, fc1T, bf1, h1);
    k_fc2 <<<dim3(1568), dim3(512), 0, stream>>>(h1, fc2T, bfc2, x1, out);
}

// Round 4
// 629.943 us; speedup vs baseline: 1.5007x; 1.5007x over previous
//
#include <hip/hip_runtime.h>
#include <math.h>

typedef unsigned short u16;
typedef unsigned int u32;
typedef __attribute__((ext_vector_type(8))) short short8;
typedef __attribute__((ext_vector_type(2))) unsigned int u32x2;
typedef __attribute__((ext_vector_type(4))) float f32x4;

#define C_ 128
#define NTOK 200704   // B*H*W = 64*56*56
#define NMT  12544    // NTOK/16 M-tiles
#define NWIN 4096     // B * 64
#define SCALE_ 0.17677669529663687f

static __device__ __forceinline__ float bf2f(u16 u) {
    return __uint_as_float(((u32)u) << 16);
}
static __device__ __forceinline__ u16 f2bf(float f) {
    u32 u = __float_as_uint(f);
    u32 r = u + 0x7FFFu + ((u >> 16) & 1u);
    return (u16)(r >> 16);
}
static __device__ __forceinline__ u32 cvtpk(float a, float b) {
    u32 r;
    asm("v_cvt_pk_bf16_f32 %0, %1, %2" : "=v"(r) : "v"(a), "v"(b));
    return r;
}

// ---------------- plain weight transpose to bf16 [N][K] ----------------
__global__ void k_transpose(const float* __restrict__ W, u16* __restrict__ Wt, int K, int N) {
    int i = blockIdx.x * 256 + threadIdx.x;
    if (i >= K * N) return;
    int k = i / N, n = i % N;
    Wt[(size_t)n * K + k] = f2bf(W[i]);
}

// ---------------- LN-folding prep: Wt[n][k]=bf16(W[k][n]*g[k]); bout[n]=b[n]+sum_k be[k]*W[k][n]
__global__ __launch_bounds__(128) void k_prep(const float* __restrict__ W,
                                              const float* __restrict__ g,
                                              const float* __restrict__ be,
                                              const float* __restrict__ b,
                                              u16* __restrict__ Wt,
                                              float* __restrict__ bout, int N) {
    int n = blockIdx.x, k = threadIdx.x;  // K = 128 fixed
    float w = W[(size_t)k * N + n];
    Wt[(size_t)n * 128 + k] = f2bf(w * g[k]);
    __shared__ float red[128];
    red[k] = be[k] * w;
    __syncthreads();
    for (int s = 64; s > 0; s >>= 1) {
        if (k < s) red[k] += red[k + s];
        __syncthreads();
    }
    if (k == 0) bout[n] = b[n] + red[0];
}

// ---------------- B-fragment loader ----------------
template <int KD, int NN>
static __device__ __forceinline__ void load_bfrag(const u16* __restrict__ Wt, int col0, int lane,
                                                  short8 (&bf)[NN][KD / 32]) {
    constexpr int NK = KD / 32;
    const int colb = lane & 15, kb = (lane >> 4) * 8;
#pragma unroll
    for (int n = 0; n < NN; ++n)
#pragma unroll
        for (int ks = 0; ks < NK; ++ks)
            bf[n][ks] = *(const short8*)(Wt + (size_t)(col0 + n * 16 + colb) * KD + ks * 32 + kb);
}

// ---------------- QKV GEMM, fused LN1 + shift + window partition ----------------
__global__ __launch_bounds__(512) void k_qkv(const float* __restrict__ x,
                                             const u16* __restrict__ qkvT,
                                             const float* __restrict__ bq,
                                             u16* __restrict__ qkvO) {
    int lane = threadIdx.x & 63, wv = threadIdx.x >> 6;
    int colb = lane & 15, q4 = lane >> 4;
    int col0 = wv * 48;
    short8 bfr[3][4];
    load_bfrag<128, 3>(qkvT, col0, lane, bfr);
    float bias[3];
#pragma unroll
    for (int n = 0; n < 3; ++n) bias[n] = bq[col0 + n * 16 + colb];
#pragma unroll 1
    for (int mt = blockIdx.x; mt < NMT; mt += gridDim.x) {
        int m = mt * 16 + colb;
        int wn = m / 49, nn = m - wn * 49;
        int b = wn >> 6, wl = wn & 63;
        int ys = (wl >> 3) * 7 + nn / 7, xs = (wl & 7) * 7 + nn % 7;
        int y = ys + 3; if (y >= 56) y -= 56;
        int xx = xs + 3; if (xx >= 56) xx -= 56;
        const float* px = x + ((size_t)b * 3136 + y * 56 + xx) * 128 + q4 * 8;
        float cur[32];
#pragma unroll
        for (int ks = 0; ks < 4; ++ks) {
            *(float4*)(cur + ks * 8)     = *(const float4*)(px + ks * 32);
            *(float4*)(cur + ks * 8 + 4) = *(const float4*)(px + ks * 32 + 4);
        }
        float s = 0.f, s2 = 0.f;
#pragma unroll
        for (int i = 0; i < 32; ++i) { s += cur[i]; s2 += cur[i] * cur[i]; }
        s  += __shfl_xor(s, 16, 64);  s  += __shfl_xor(s, 32, 64);
        s2 += __shfl_xor(s2, 16, 64); s2 += __shfl_xor(s2, 32, 64);
        float mu = s * (1.f / 128.f);
        float rs = rsqrtf(s2 * (1.f / 128.f) - mu * mu + 1e-3f);
        short8 af[4];
#pragma unroll
        for (int ks = 0; ks < 4; ++ks)
#pragma unroll
            for (int e = 0; e < 8; ++e)
                af[ks][e] = (short)f2bf((cur[ks * 8 + e] - mu) * rs);
        f32x4 acc[3];
#pragma unroll
        for (int n = 0; n < 3; ++n) acc[n] = (f32x4){0.f, 0.f, 0.f, 0.f};
#pragma unroll
        for (int ks = 0; ks < 4; ++ks)
#pragma unroll
            for (int n = 0; n < 3; ++n)
                acc[n] = __builtin_amdgcn_mfma_f32_16x16x32_bf16(af[ks], bfr[n][ks], acc[n], 0, 0, 0);
#pragma unroll
        for (int n = 0; n < 3; ++n) {
            int col = col0 + n * 16 + colb;
#pragma unroll
            for (int r = 0; r < 4; ++r)
                qkvO[(size_t)(mt * 16 + q4 * 4 + r) * 384 + col] = f2bf(acc[n][r] + bias[n]);
        }
    }
}

// ---------------- MFMA window attention: 1 block/window, 1 wave/head ----------------
__global__ __launch_bounds__(256) void k_attn(const u16* __restrict__ qkv,
                                              const float* __restrict__ relTab,
                                              u16* __restrict__ outA) {
    __shared__ u16 Pl[4 * 64 * 64];      // per-head P [64 r][64 j], XOR-swizzled, 32KB
    __shared__ u16 Vt[4 * 32 * 72];      // V transposed [h][d][j], stride 72, 18KB
    __shared__ float biasl[676];
    __shared__ int regl[64];
    int tid = threadIdx.x;
    int w = blockIdx.x;
    int wi = w & 63, wr = wi >> 3, wc = wi & 7;
    const u16* base = qkv + (size_t)w * 49 * 384;

    // stage V transposed: task = (row=h*32+d, j-octet); coalesced 2B global reads, b128 LDS writes
    for (int task = tid; task < 1024; task += 256) {
        int row = task >> 3, jo = (task & 7) * 8;
        int h = row >> 5, d = row & 31;
        short8 v;
#pragma unroll
        for (int e = 0; e < 8; ++e) {
            int j = jo + e;
            v[e] = (j < 49) ? (short)base[j * 384 + 256 + h * 32 + d] : (short)0;
        }
        *(short8*)(Vt + row * 72 + jo) = v;
    }
    for (int idx = tid; idx < 676; idx += 256) biasl[idx] = relTab[idx];
    if (tid < 64) {
        int t = tid;
        int ty = t / 7, tx = t - ty * 7;
        int gy = wr * 7 + ty, gx = wc * 7 + tx;
        int rg = (gy < 49 ? 0 : (gy < 53 ? 1 : 2)) * 3 + (gx < 49 ? 0 : (gx < 53 ? 1 : 2));
        regl[t] = (t < 49) ? rg : 99;
    }
    __syncthreads();

    int lane = tid & 63, h = tid >> 6;
    int colb = lane & 15, q4 = lane >> 4;

    // ---- QK^T (swapped): acc[mt][nt] = S^T[j = mt*16+q4*4+reg][r = nt*16+colb]
    short8 ka[4], qb[4];
#pragma unroll
    for (int t = 0; t < 4; ++t) {
        int row = w * 49 + t * 16 + colb;
        if (row > NTOK - 1) row = NTOK - 1;
        ka[t] = *(const short8*)(qkv + (size_t)row * 384 + 128 + h * 32 + q4 * 8);
        qb[t] = *(const short8*)(qkv + (size_t)row * 384 + h * 32 + q4 * 8);
    }
    float s[4][4][4];  // [mt][nt][reg]
    {
        f32x4 acc[4][4];
#pragma unroll
        for (int mt = 0; mt < 4; ++mt)
#pragma unroll
            for (int nt = 0; nt < 4; ++nt)
                acc[mt][nt] = __builtin_amdgcn_mfma_f32_16x16x32_bf16(
                    ka[mt], qb[nt], (f32x4){0.f, 0.f, 0.f, 0.f}, 0, 0, 0);
        // ---- bias + mask
        int bc[4], rc[4];
#pragma unroll
        for (int nt = 0; nt < 4; ++nt) {
            int c = nt * 16 + colb;
            int cc = c < 49 ? c : 48;
            int yc = cc / 7, xc = cc - yc * 7;
            bc[nt] = ((yc + 6) * 13 + (xc + 6)) * 4 + h;
            rc[nt] = regl[cc];
        }
#pragma unroll
        for (int mt = 0; mt < 4; ++mt)
#pragma unroll
            for (int reg = 0; reg < 4; ++reg) {
                int j = mt * 16 + q4 * 4 + reg;
                int jj = j < 49 ? j : 48;
                int yj = jj / 7, xj = jj - yj * 7;
                int oj = (yj * 13 + xj) * 4;
                int rj = regl[jj];
#pragma unroll
                for (int nt = 0; nt < 4; ++nt) {
                    float v = acc[mt][nt][reg] * SCALE_ + biasl[bc[nt] - oj];
                    if (rj != rc[nt]) v -= 100.f;
                    s[mt][nt][reg] = (j < 49) ? v : -1e30f;
                }
            }
    }
    // ---- softmax over j (rows): in-lane over 16 + shfl over q4 groups
    float sm[4];
#pragma unroll
    for (int nt = 0; nt < 4; ++nt) {
        float m = s[0][nt][0];
#pragma unroll
        for (int mt = 0; mt < 4; ++mt)
#pragma unroll
            for (int reg = 0; reg < 4; ++reg) m = fmaxf(m, s[mt][nt][reg]);
        m = fmaxf(m, __shfl_xor(m, 16, 64));
        m = fmaxf(m, __shfl_xor(m, 32, 64));
        float t = 0.f;
#pragma unroll
        for (int mt = 0; mt < 4; ++mt)
#pragma unroll
            for (int reg = 0; reg < 4; ++reg) {
                float e = __expf(s[mt][nt][reg] - m);
                s[mt][nt][reg] = e;
                t += e;
            }
        t += __shfl_xor(t, 16, 64);
        t += __shfl_xor(t, 32, 64);
        sm[nt] = 1.f / t;
    }
    // ---- pack P to bf16, write to swizzled LDS (wave-private: no barrier needed)
    u16* Ph = Pl + h * 4096;
#pragma unroll
    for (int nt = 0; nt < 4; ++nt) {
        int r = nt * 16 + colb;
        u32 sw = (u32)(r & 7) << 4;
#pragma unroll
        for (int mt = 0; mt < 4; ++mt) {
            u32x2 pk;
            pk[0] = cvtpk(s[mt][nt][0] * sm[nt], s[mt][nt][1] * sm[nt]);
            pk[1] = cvtpk(s[mt][nt][2] * sm[nt], s[mt][nt][3] * sm[nt]);
            u32 off = ((u32)((r * 64 + mt * 16 + q4 * 4) * 2)) ^ sw;
            *(u32x2*)((char*)Ph + off) = pk;
        }
    }
    // ---- PV: out[r][d] = sum_j P[r][j] V[j][d]
    short8 vb[2][2];
#pragma unroll
    for (int no = 0; no < 2; ++no)
#pragma unroll
        for (int ks = 0; ks < 2; ++ks)
            vb[no][ks] = *(const short8*)(Vt + (h * 32 + no * 16 + colb) * 72 + ks * 32 + q4 * 8);
#pragma unroll
    for (int mo = 0; mo < 4; ++mo) {
        int r = mo * 16 + colb;
        u32 sw = (u32)(r & 7) << 4;
        short8 pa[2];
#pragma unroll
        for (int ks = 0; ks < 2; ++ks) {
            u32 off = ((u32)((r * 64 + ks * 32 + q4 * 8) * 2)) ^ sw;
            pa[ks] = *(const short8*)((const char*)Ph + off);
        }
        f32x4 o0 = {0.f, 0.f, 0.f, 0.f}, o1 = {0.f, 0.f, 0.f, 0.f};
#pragma unroll
        for (int ks = 0; ks < 2; ++ks) {
            o0 = __builtin_amdgcn_mfma_f32_16x16x32_bf16(pa[ks], vb[0][ks], o0, 0, 0, 0);
            o1 = __builtin_amdgcn_mfma_f32_16x16x32_bf16(pa[ks], vb[1][ks], o1, 0, 0, 0);
        }
#pragma unroll
        for (int reg = 0; reg < 4; ++reg) {
            int orow = mo * 16 + q4 * 4 + reg;
            if (orow < 49) {
                size_t o = ((size_t)w * 49 + orow) * 128 + h * 32;
                outA[o + colb]      = f2bf(o0[reg]);
                outA[o + 16 + colb] = f2bf(o1[reg]);
            }
        }
    }
}

// ---------------- proj GEMM + reverse/roll + residual -> x1 (bf16) ----------------
__global__ __launch_bounds__(512) void k_proj(const u16* __restrict__ attnO,
                                              const u16* __restrict__ projT,
                                              const float* __restrict__ bproj,
                                              const float* __restrict__ x,
                                              u16* __restrict__ x1) {
    int lane = threadIdx.x & 63, wv = threadIdx.x >> 6;
    int colb = lane & 15, q4 = lane >> 4;
    int col0 = wv * 16;
    short8 bfr[1][4];
    load_bfrag<128, 1>(projT, col0, lane, bfr);
    float bias = bproj[col0 + colb];
#pragma unroll 1
    for (int mt = blockIdx.x; mt < NMT; mt += gridDim.x) {
        const u16* pa = attnO + (size_t)(mt * 16 + colb) * 128 + q4 * 8;
        short8 af[4];
#pragma unroll
        for (int ks = 0; ks < 4; ++ks) af[ks] = *(const short8*)(pa + ks * 32);
        f32x4 acc = {0.f, 0.f, 0.f, 0.f};
#pragma unroll
        for (int ks = 0; ks < 4; ++ks)
            acc = __builtin_amdgcn_mfma_f32_16x16x32_bf16(af[ks], bfr[0][ks], acc, 0, 0, 0);
        int col = col0 + colb;
#pragma unroll
        for (int r = 0; r < 4; ++r) {
            int m = mt * 16 + q4 * 4 + r;
            int wn = m / 49, nn = m - wn * 49;
            int b = wn >> 6, wl = wn & 63;
            int ys = (wl >> 3) * 7 + nn / 7, xs = (wl & 7) * 7 + nn % 7;
            int y = ys + 3; if (y >= 56) y -= 56;
            int xx = xs + 3; if (xx >= 56) xx -= 56;
            size_t tok = (size_t)b * 3136 + y * 56 + xx;
            x1[tok * 128 + col] = f2bf(acc[r] + bias + x[tok * 128 + col]);
        }
    }
}

// ---------------- FC1, fused LN2 + exact GELU: wave owns 64 cols ----------------
__global__ __launch_bounds__(512) void k_fc1(const u16* __restrict__ x1,
                                             const u16* __restrict__ fc1T,
                                             const float* __restrict__ b1,
                                             u16* __restrict__ h1) {
    int lane = threadIdx.x & 63, wv = threadIdx.x >> 6;
    int colb = lane & 15, q4 = lane >> 4;
    int col0 = wv * 64;
    short8 bfr[4][4];
    load_bfrag<128, 4>(fc1T, col0, lane, bfr);
    float bias[4];
#pragma unroll
    for (int n = 0; n < 4; ++n) bias[n] = b1[col0 + n * 16 + colb];
#pragma unroll 1
    for (int mt = blockIdx.x; mt < NMT; mt += gridDim.x) {
        const u16* px = x1 + (size_t)(mt * 16 + colb) * 128 + q4 * 8;
        short8 raw[4];
#pragma unroll
        for (int ks = 0; ks < 4; ++ks) raw[ks] = *(const short8*)(px + ks * 32);
        float cur[32];
#pragma unroll
        for (int ks = 0; ks < 4; ++ks)
#pragma unroll
            for (int e = 0; e < 8; ++e) cur[ks * 8 + e] = bf2f((u16)raw[ks][e]);
        float s = 0.f, s2 = 0.f;
#pragma unroll
        for (int i = 0; i < 32; ++i) { s += cur[i]; s2 += cur[i] * cur[i]; }
        s  += __shfl_xor(s, 16, 64);  s  += __shfl_xor(s, 32, 64);
        s2 += __shfl_xor(s2, 16, 64); s2 += __shfl_xor(s2, 32, 64);
        float mu = s * (1.f / 128.f);
        float rs = rsqrtf(s2 * (1.f / 128.f) - mu * mu + 1e-3f);
        short8 af[4];
#pragma unroll
        for (int ks = 0; ks < 4; ++ks)
#pragma unroll
            for (int e = 0; e < 8; ++e)
                af[ks][e] = (short)f2bf((cur[ks * 8 + e] - mu) * rs);
        f32x4 acc[4];
#pragma unroll
        for (int n = 0; n < 4; ++n) acc[n] = (f32x4){0.f, 0.f, 0.f, 0.f};
#pragma unroll
        for (int ks = 0; ks < 4; ++ks)
#pragma unroll
            for (int n = 0; n < 4; ++n)
                acc[n] = __builtin_amdgcn_mfma_f32_16x16x32_bf16(af[ks], bfr[n][ks], acc[n], 0, 0, 0);
#pragma unroll
        for (int n = 0; n < 4; ++n) {
            int col = col0 + n * 16 + colb;
#pragma unroll
            for (int r = 0; r < 4; ++r) {
                float t = acc[n][r] + bias[n];
                float g = 0.5f * t * (1.f + erff(t * 0.70710678118654752f));
                h1[(size_t)(mt * 16 + q4 * 4 + r) * 512 + col] = f2bf(g);
            }
        }
    }
}

// ---------------- FC2 + final residual ----------------
__global__ __launch_bounds__(512) void k_fc2(const u16* __restrict__ h1,
                                             const u16* __restrict__ fc2T,
                                             const float* __restrict__ b2,
                                             const u16* __restrict__ x1,
                                             float* __restrict__ out) {
    int lane = threadIdx.x & 63, wv = threadIdx.x >> 6;
    int colb = lane & 15, q4 = lane >> 4;
    int col0 = wv * 16;
    short8 bfr[1][16];
    load_bfrag<512, 1>(fc2T, col0, lane, bfr);
    float bias = b2[col0 + colb];
#pragma unroll 1
    for (int mt = blockIdx.x; mt < NMT; mt += gridDim.x) {
        const u16* pa = h1 + (size_t)(mt * 16 + colb) * 512 + q4 * 8;
        short8 af[16];
#pragma unroll
        for (int ks = 0; ks < 16; ++ks) af[ks] = *(const short8*)(pa + ks * 32);
        f32x4 acc = {0.f, 0.f, 0.f, 0.f};
#pragma unroll
        for (int ks = 0; ks < 16; ++ks)
            acc = __builtin_amdgcn_mfma_f32_16x16x32_bf16(af[ks], bfr[0][ks], acc, 0, 0, 0);
        int col = col0 + colb;
#pragma unroll
        for (int r = 0; r < 4; ++r) {
            size_t m = (size_t)mt * 16 + q4 * 4 + r;
            out[m * 128 + col] = bf2f(x1[m * 128 + col]) + acc[r] + bias;
        }
    }
}

extern "C" void kernel_launch(void* const* d_in, const int* in_sizes, int n_in,
                              void* d_out, int out_size, void* d_ws, size_t ws_size,
                              hipStream_t stream) {
    const float* x    = (const float*)d_in[0];
    const float* g1   = (const float*)d_in[1];
    const float* be1  = (const float*)d_in[2];
    const float* Wqkv = (const float*)d_in[3];
    const float* bqkv = (const float*)d_in[4];
    const float* relT = (const float*)d_in[5];
    const float* Wproj= (const float*)d_in[6];
    const float* bproj= (const float*)d_in[7];
    const float* g2   = (const float*)d_in[8];
    const float* be2  = (const float*)d_in[9];
    const float* Wfc1 = (const float*)d_in[10];
    const float* bfc1 = (const float*)d_in[11];
    const float* Wfc2 = (const float*)d_in[12];
    const float* bfc2 = (const float*)d_in[13];
    float* out = (float*)d_out;
    char* ws = (char*)d_ws;

    u16* qkvb  = (u16*)(ws + 0);              // 154,140,672  dead after k_attn
    u16* attnO = (u16*)(ws + 154140672ULL);   //  51,380,224  dead after k_proj
    u16* x1    = (u16*)(ws + 205520896ULL);   //  51,380,224  lives to k_fc2
    u16* h1    = (u16*)(ws + 0);              // 205,520,896  overwrites qkvb/attnO
    char* wb   = ws + 256901120ULL;
    u16* qkvT  = (u16*)(wb);                  // 98,304
    float* bq  = (float*)(wb + 98304);        // 1,536
    u16* fc1T  = (u16*)(wb + 99840);          // 131,072
    float* bf1 = (float*)(wb + 230912);       // 2,048
    u16* projT = (u16*)(wb + 232960);         // 32,768
    u16* fc2T  = (u16*)(wb + 265728);         // 131,072

    k_prep<<<dim3(384), dim3(128), 0, stream>>>(Wqkv, g1, be1, bqkv, qkvT, bq, 384);
    k_prep<<<dim3(512), dim3(128), 0, stream>>>(Wfc1, g2, be2, bfc1, fc1T, bf1, 512);
    k_transpose<<<dim3((128 * 128 + 255) / 256), dim3(256), 0, stream>>>(Wproj, projT, 128, 128);
    k_transpose<<<dim3((512 * 128 + 255) / 256), dim3(256), 0, stream>>>(Wfc2, fc2T, 512, 128);

    k_qkv <<<dim3(1024), dim3(512), 0, stream>>>(x, qkvT, bq, qkvb);
    k_attn<<<dim3(NWIN), dim3(256), 0, stream>>>(qkvb, relT, attnO);
    k_proj<<<dim3(1024), dim3(512), 0, stream>>>(attnO, projT, bproj, x, x1);
    k_fc1 <<<dim3(1024), dim3(512), 0, stream>>>(x1, fc1T, bf1, h1);
    k_fc2 <<<dim3(1024), dim3(512), 0, stream>>>(h1, fc2T, bfc2, x1, out);
}